// Round 13
// baseline (122.526 us; speedup 1.0000x reference)
//
#include <hip/hip_runtime.h>

typedef float f32x4 __attribute__((ext_vector_type(4)));
typedef float f32x16 __attribute__((ext_vector_type(16)));
typedef short short8 __attribute__((ext_vector_type(8)));
typedef short short4_t __attribute__((ext_vector_type(4)));

#define GLOAD_LDS16(gp, lp) \
  __builtin_amdgcn_global_load_lds((const __attribute__((address_space(1))) void*)(gp), \
                                   (__attribute__((address_space(3))) void*)(lp), 16, 0, 0)

__device__ __forceinline__ short f2bf(float f){
  unsigned u = __builtin_bit_cast(unsigned, f);
  u += 0x7fffu + ((u >> 16) & 1u);   // RNE, no NaN inputs here
  return (short)(u >> 16);
}

__device__ __forceinline__ float exp2_fast(float x){
  return __builtin_amdgcn_exp2f(x);  // v_exp_f32: 2^x
}

// ---------------- fused prep: x fp32->bf16, w_qkv/w_out transpose+cvt ----------------
__global__ __launch_bounds__(256) void prep_kernel(
    const float* __restrict__ x, const float* __restrict__ wqkv,
    const float* __restrict__ wout, short* __restrict__ xb,
    short* __restrict__ wqkvT, short* __restrict__ woutT)
{
  __shared__ float tile[32][33];
  const int bid = blockIdx.x, tid = threadIdx.x;
  if (bid < 512){
    int base = bid*2048 + tid;          // 2048 float4 per block
    #pragma unroll
    for (int it=0; it<8; it++){
      int i = base + it*256;
      f32x4 v = ((const f32x4*)x)[i];
      short4_t s;
      s[0]=f2bf(v[0]); s[1]=f2bf(v[1]); s[2]=f2bf(v[2]); s[3]=f2bf(v[3]);
      ((short4_t*)xb)[i] = s;
    }
    return;
  }
  const float* w; short* wT; int N, idx;
  if (bid < 3584){ w = wqkv; wT = wqkvT; N = 3072; idx = bid - 512;  }
  else           { w = wout; wT = woutT; N = 1024; idx = bid - 3584; }
  const int K = 1024;
  int bn = (idx % (N >> 5)) * 32, bk = (idx / (N >> 5)) * 32;
  int tx = tid & 31, ty = tid >> 5;
  #pragma unroll
  for (int r=ty; r<32; r+=8) tile[r][tx] = w[(size_t)(bk+r)*N + bn + tx];
  __syncthreads();
  #pragma unroll
  for (int r=ty; r<32; r+=8) wT[(size_t)(bn+r)*K + bk + tx] = f2bf(tile[tx][r]);
}

// ============ 256x256 8-phase GEMM (T2+T3+T4+T5): C = A[M][K] * Bt[N][K]^T ============
// 512 threads = 8 waves (2M x 4N); per-wave 128x64 via acc[8][4] of 16x16x32 MFMA.
// LDS = ring of 8 half-slots x 16KB (128 KiB). Half = K-slice (32 cols) of A or B
// (256 rows x 32). Halves of tile t: slots (4t+{0:Ak0,1:Bk0,2:Ak1,3:Bk1})&7.
// Phases P1/P2 consume k0, P3/P4 consume k1 -> staggered; stage one half of t+1
// per phase; counted vmcnt(4) at P2/P4 only (never 0 mid-loop).
// Swizzle: stored unit u ^ ((row^(row>>2))&3) -> 2 lanes/bank (free); source
// pre-swizzled for linear global_load_lds (Rule 21).
template<int MODE>
__global__ __launch_bounds__(512) void gemm256_kernel(
    const short* __restrict__ A, const short* __restrict__ Bt,
    float* __restrict__ Cf, short* __restrict__ qb_, short* __restrict__ kb_,
    short* __restrict__ vb_, int M, int N, int K)
{
  __shared__ short lds[8*8192];   // 128 KiB
  const int tid = threadIdx.x, lane = tid & 63;
  const int l15 = lane & 15, lg = (lane >> 4) & 3;
  const int w  = tid >> 6;             // 0..7
  const int wm = w >> 2, wn = w & 3;   // 2 x 4
  const int m0 = blockIdx.x * 256, n0 = blockIdx.y * 256;

  // staging per-thread constants (2 gload_lds per half: rows r0, r1)
  const int r0 = tid >> 2, r1 = 128 + r0;
  const int c0 = tid & 3;
  const int u0 = c0 ^ ((r0 ^ (r0 >> 2)) & 3);
  const int u1 = c0 ^ ((r1 ^ (r1 >> 2)) & 3);
  const short* pA0 = A  + (size_t)(m0 + r0)*K + u0*8;
  const short* pA1 = A  + (size_t)(m0 + r1)*K + u1*8;
  const short* pB0 = Bt + (size_t)(n0 + r0)*K + u0*8;
  const short* pB1 = Bt + (size_t)(n0 + r1)*K + u1*8;
  const int d0 = (tid & ~63)*8;          // LDS dest (shorts), i=0
  const int d1 = (512 + (tid & ~63))*8;  // i=1

  // frag-read byte offsets (swizzle depends only on l15)
  const int su = (l15 ^ (l15 >> 2)) & 3;
  const int abase = (wm*128 + l15)*64 + ((lg ^ su) << 4);  // + m*1024 bytes
  const int bbase = (wn*64  + l15)*64 + ((lg ^ su) << 4);  // + n*1024 bytes

  f32x4 acc[8][4];
  #pragma unroll
  for (int m=0;m<8;m++)
    #pragma unroll
    for (int n=0;n<4;n++) acc[m][n] = (f32x4){0.f,0.f,0.f,0.f};

  auto stage = [&](const short* p0, const short* p1, int kcol, int slot){
    GLOAD_LDS16(p0 + kcol, &lds[slot*8192 + d0]);
    GLOAD_LDS16(p1 + kcol, &lds[slot*8192 + d1]);
  };

  const int NT = K >> 6;   // K-tiles of 64
  // prologue: all 4 halves of tile 0
  stage(pA0, pA1, 0,  0);
  stage(pB0, pB1, 0,  1);
  stage(pA0, pA1, 32, 2);
  stage(pB0, pB1, 32, 3);
  asm volatile("s_waitcnt vmcnt(4)" ::: "memory");   // Ak0(0), Bk0(0) resident
  __builtin_amdgcn_s_barrier();

  for (int t = 0; t < NT; ++t){
    const int b = (t*4) & 7;
    const char* LA0 = (const char*)lds + (size_t)b*16384;
    const char* LB0 = (const char*)lds + (size_t)((b+1)&7)*16384;
    const char* LA1 = (const char*)lds + (size_t)((b+2)&7)*16384;
    const char* LB1 = (const char*)lds + (size_t)((b+3)&7)*16384;
    const int nk = (t+1)*64;
    const bool pf = (t+1 < NT);
    short8 af[8], bf[4];

    // ---- P1: read A-k0 (8) + B-k0 n0,n1; stage Ak0(t+1)
    #pragma unroll
    for (int m=0;m<8;m++) af[m] = *(const short8*)(LA0 + abase + m*1024);
    bf[0] = *(const short8*)(LB0 + bbase);
    bf[1] = *(const short8*)(LB0 + bbase + 1024);
    if (pf) stage(pA0, pA1, nk, (b+4)&7);
    __builtin_amdgcn_s_barrier();
    asm volatile("s_waitcnt lgkmcnt(0)" ::: "memory");
    __builtin_amdgcn_sched_barrier(0);
    __builtin_amdgcn_s_setprio(1);
    #pragma unroll
    for (int m=0;m<8;m++){
      acc[m][0] = __builtin_amdgcn_mfma_f32_16x16x32_bf16(af[m], bf[0], acc[m][0], 0,0,0);
      acc[m][1] = __builtin_amdgcn_mfma_f32_16x16x32_bf16(af[m], bf[1], acc[m][1], 0,0,0);
    }
    __builtin_amdgcn_s_setprio(0);
    __builtin_amdgcn_s_barrier();

    // ---- P2: read B-k0 n2,n3; stage Bk0(t+1); vmcnt(4)
    bf[2] = *(const short8*)(LB0 + bbase + 2048);
    bf[3] = *(const short8*)(LB0 + bbase + 3072);
    if (pf){ stage(pB0, pB1, nk, (b+5)&7);
             asm volatile("s_waitcnt vmcnt(4)" ::: "memory"); }
    else   { asm volatile("s_waitcnt vmcnt(0)" ::: "memory"); }
    __builtin_amdgcn_s_barrier();
    asm volatile("s_waitcnt lgkmcnt(0)" ::: "memory");
    __builtin_amdgcn_sched_barrier(0);
    __builtin_amdgcn_s_setprio(1);
    #pragma unroll
    for (int m=0;m<8;m++){
      acc[m][2] = __builtin_amdgcn_mfma_f32_16x16x32_bf16(af[m], bf[2], acc[m][2], 0,0,0);
      acc[m][3] = __builtin_amdgcn_mfma_f32_16x16x32_bf16(af[m], bf[3], acc[m][3], 0,0,0);
    }
    __builtin_amdgcn_s_setprio(0);
    __builtin_amdgcn_s_barrier();

    // ---- P3: read A-k1 (8) + B-k1 n0,n1; stage Ak1(t+1)
    #pragma unroll
    for (int m=0;m<8;m++) af[m] = *(const short8*)(LA1 + abase + m*1024);
    bf[0] = *(const short8*)(LB1 + bbase);
    bf[1] = *(const short8*)(LB1 + bbase + 1024);
    if (pf) stage(pA0, pA1, nk + 32, (b+6)&7);
    __builtin_amdgcn_s_barrier();
    asm volatile("s_waitcnt lgkmcnt(0)" ::: "memory");
    __builtin_amdgcn_sched_barrier(0);
    __builtin_amdgcn_s_setprio(1);
    #pragma unroll
    for (int m=0;m<8;m++){
      acc[m][0] = __builtin_amdgcn_mfma_f32_16x16x32_bf16(af[m], bf[0], acc[m][0], 0,0,0);
      acc[m][1] = __builtin_amdgcn_mfma_f32_16x16x32_bf16(af[m], bf[1], acc[m][1], 0,0,0);
    }
    __builtin_amdgcn_s_setprio(0);
    __builtin_amdgcn_s_barrier();

    // ---- P4: read B-k1 n2,n3; stage Bk1(t+1); vmcnt(4)
    bf[2] = *(const short8*)(LB1 + bbase + 2048);
    bf[3] = *(const short8*)(LB1 + bbase + 3072);
    if (pf){ stage(pB0, pB1, nk + 32, (b+7)&7);
             asm volatile("s_waitcnt vmcnt(4)" ::: "memory"); }
    else   { asm volatile("s_waitcnt vmcnt(0)" ::: "memory"); }
    __builtin_amdgcn_s_barrier();
    asm volatile("s_waitcnt lgkmcnt(0)" ::: "memory");
    __builtin_amdgcn_sched_barrier(0);
    __builtin_amdgcn_s_setprio(1);
    #pragma unroll
    for (int m=0;m<8;m++){
      acc[m][2] = __builtin_amdgcn_mfma_f32_16x16x32_bf16(af[m], bf[2], acc[m][2], 0,0,0);
      acc[m][3] = __builtin_amdgcn_mfma_f32_16x16x32_bf16(af[m], bf[3], acc[m][3], 0,0,0);
    }
    __builtin_amdgcn_s_setprio(0);
    __builtin_amdgcn_s_barrier();
  }

  // epilogue: D layout col = lane&15, row = (lane>>4)*4 + r
  #pragma unroll
  for (int m=0;m<8;m++){
    #pragma unroll
    for (int n=0;n<4;n++){
      int col = n0 + wn*64 + n*16 + l15;
      #pragma unroll
      for (int r=0;r<4;r++){
        int rowg = m0 + wm*128 + m*16 + lg*4 + r;
        float v = acc[m][n][r];
        if (MODE == 0){
          Cf[(size_t)rowg*N + col] = v;
        } else {
          int three = col >> 10, hh = (col >> 6) & 15, e = col & 63;
          int bb = rowg >> 11, t = rowg & 2047;
          int bh = bb*16 + hh;
          if (three == 0)      qb_[((size_t)bh*2048 + t)*64 + e] = f2bf(v * (0.125f*1.44269504f));
          else if (three == 1) kb_[((size_t)bh*2048 + t)*64 + e] = f2bf(v);
          else                 vb_[((size_t)bh*2048 + t)*64 + e] = f2bf(v);
        }
      }
    }
  }
}

// ---------------- 128x128 bf16 GEMM (kept for out-proj): C = A * Bt^T ----------------
__global__ __launch_bounds__(256) void gemm128_kernel(
    const short* __restrict__ A, const short* __restrict__ Bt,
    float* __restrict__ Cf, int M, int N, int K)
{
  __shared__ short a_lds[128*64];
  __shared__ short b_lds[128*64];
  const int tid = threadIdx.x;
  const int lane = tid & 63;
  const int l15 = lane & 15, lg = lane >> 4;
  const int w  = tid >> 6;
  const int wr = w >> 1, wc = w & 1;
  const int m0 = blockIdx.x * 128, n0 = blockIdx.y * 128;

  f32x4 acc[4][4];
  #pragma unroll
  for (int i=0;i<4;i++)
    #pragma unroll
    for (int j=0;j<4;j++) acc[i][j] = (f32x4){0.f,0.f,0.f,0.f};

  for (int kt = 0; kt < K; kt += 64){
    __syncthreads();
    #pragma unroll
    for (int i=0;i<4;i++){
      int u = i*256 + tid;
      int row = u >> 3, cu = u & 7;
      int kl = ((cu ^ (row & 7)) << 3);
      GLOAD_LDS16(A + (size_t)(m0+row)*K + kt + kl, a_lds + (size_t)(i*256 + (tid & ~63))*8);
    }
    #pragma unroll
    for (int i=0;i<4;i++){
      int u = i*256 + tid;
      int row = u >> 3, cu = u & 7;
      int kl = ((cu ^ (row & 7)) << 3);
      GLOAD_LDS16(Bt + (size_t)(n0+row)*K + kt + kl, b_lds + (size_t)(i*256 + (tid & ~63))*8);
    }
    asm volatile("s_waitcnt vmcnt(0)" ::: "memory");
    __syncthreads();

    #pragma unroll
    for (int kk=0;kk<2;kk++){
      short8 af[4], bfr[4];
      #pragma unroll
      for (int mi=0;mi<4;mi++){
        int row = wr*64 + mi*16 + l15;
        int uu = ((kk*4 + lg) ^ (row & 7));
        af[mi] = *(const short8*)&a_lds[row*64 + uu*8];
      }
      #pragma unroll
      for (int ni=0;ni<4;ni++){
        int row = wc*64 + ni*16 + l15;
        int uu = ((kk*4 + lg) ^ (row & 7));
        bfr[ni] = *(const short8*)&b_lds[row*64 + uu*8];
      }
      #pragma unroll
      for (int mi=0;mi<4;mi++)
        #pragma unroll
        for (int ni=0;ni<4;ni++)
          acc[mi][ni] = __builtin_amdgcn_mfma_f32_16x16x32_bf16(af[mi], bfr[ni], acc[mi][ni], 0,0,0);
    }
  }

  #pragma unroll
  for (int mi=0;mi<4;mi++){
    #pragma unroll
    for (int ni=0;ni<4;ni++){
      int col = n0 + wc*64 + ni*16 + l15;
      #pragma unroll
      for (int r=0;r<4;r++){
        int rowg = m0 + wr*64 + mi*16 + lg*4 + r;
        Cf[(size_t)rowg*N + col] = acc[mi][ni][r];
      }
    }
  }
}

// ---------------- V transpose: [bh][t][64] -> [bh][64][t] (bf16, LDS-tiled) ----------------
__global__ __launch_bounds__(256) void transpose_v_kernel(const short* __restrict__ vb,
                                                          short* __restrict__ vtb){
  __shared__ short tl[64][66];
  const int bh = blockIdx.x >> 5, t0 = (blockIdx.x & 31)*64;
  const int r = threadIdx.x >> 2, c4 = (threadIdx.x & 3)*16;
  const short* src = vb + ((size_t)bh*2048 + t0 + r)*64 + c4;
  short8 a0 = *(const short8*)(src);
  short8 a1 = *(const short8*)(src + 8);
  #pragma unroll
  for (int j=0;j<8;j++) tl[r][c4+j] = a0[j];
  #pragma unroll
  for (int j=0;j<8;j++) tl[r][c4+8+j] = a1[j];
  __syncthreads();
  short8 b0, b1;
  #pragma unroll
  for (int j=0;j<8;j++) b0[j] = tl[c4+j][r];
  #pragma unroll
  for (int j=0;j<8;j++) b1[j] = tl[c4+8+j][r];
  short* dst = vtb + ((size_t)bh*64 + r)*2048 + t0 + c4;
  *(short8*)dst = b0;
  *(short8*)(dst+8) = b1;
}

// ---------------- causal flash attention, 32x32 MFMA, P-in-register ----------------
__global__ __launch_bounds__(256) void attn_kernel(
    const short* __restrict__ q, const short* __restrict__ kbuf,
    const short* __restrict__ vt, short* __restrict__ ob)
{
  __shared__ short k_lds[2][128*64];      // [kv][k]
  __shared__ short v_lds[2][64*128];      // [d][kv] (V^T)

  const int tid = threadIdx.x, lane = tid & 63, w = tid >> 6;  // w 0..3
  const int l31 = lane & 31, hi = lane >> 5;
  const int qi = blockIdx.x >> 5;
  const int qb = (qi < 8) ? (15 - qi) : (qi - 8);   // paired blocks sum to 17 tiles
  const int bh = blockIdx.x & 31;
  const int q0 = qb * 128;

  const short* qg = q + ((size_t)bh*2048 + q0 + w*32 + l31)*64 + hi*8;
  short8 qf[4];
  #pragma unroll
  for (int kk=0;kk<4;kk++) qf[kk] = *(const short8*)(qg + kk*16);

  f32x16 o_acc[2];
  #pragma unroll
  for (int oc=0;oc<2;oc++)
    #pragma unroll
    for (int r=0;r<16;r++) o_acc[oc][r] = 0.f;
  float mreg = -1e30f, lreg = 0.f;

  const int sw = l31 & 7;
  int kro[4], vro[8];
  #pragma unroll
  for (int kk=0;kk<4;kk++) kro[kk] = l31*128 + (((kk*2+hi)^sw) << 4);
  #pragma unroll
  for (int ks=0;ks<8;ks++) vro[ks] = l31*256 + (((ks*2+hi)^sw) << 4);

  const int xk = ((tid & 7) ^ ((tid >> 3) & 7)) * 8;
  const int xv = ((tid & 15) ^ ((tid >> 4) & 7)) * 8;
  const short* kp = kbuf + (size_t)bh*2048*64 + (size_t)(tid >> 3)*64 + xk;
  const short* vp = vt   + (size_t)bh*64*2048 + (size_t)(tid >> 4)*2048 + xv;
  const int dst = (tid & ~63)*8;

  const int n = qb + 1;
  #pragma unroll
  for (int i=0;i<4;i++) GLOAD_LDS16(kp + i*2048,  &k_lds[0][i*2048 + dst]);
  #pragma unroll
  for (int i=0;i<4;i++) GLOAD_LDS16(vp + i*32768, &v_lds[0][i*2048 + dst]);
  kp += 8192; vp += 128;

  for (int s = 0; s < n; s++){
    const int cur = s & 1;
    if (s + 1 < n){
      #pragma unroll
      for (int i=0;i<4;i++) GLOAD_LDS16(kp + i*2048,  &k_lds[cur^1][i*2048 + dst]);
      #pragma unroll
      for (int i=0;i<4;i++) GLOAD_LDS16(vp + i*32768, &v_lds[cur^1][i*2048 + dst]);
      kp += 8192; vp += 128;
      asm volatile("s_waitcnt vmcnt(8)" ::: "memory");
    } else {
      asm volatile("s_waitcnt vmcnt(0)" ::: "memory");
    }
    __builtin_amdgcn_s_barrier();

    const char* kl_ = (const char*)&k_lds[cur][0];
    const char* vl_ = (const char*)&v_lds[cur][0];

    f32x16 sacc[4];
    #pragma unroll
    for (int ct=0;ct<4;ct++)
      #pragma unroll
      for (int r=0;r<16;r++) sacc[ct][r] = 0.f;
    __builtin_amdgcn_s_setprio(1);
    #pragma unroll
    for (int kk=0;kk<4;kk++){
      #pragma unroll
      for (int ct=0;ct<4;ct++){
        short8 kf = *(const short8*)(kl_ + kro[kk] + ct*4096);
        sacc[ct] = __builtin_amdgcn_mfma_f32_32x32x16_bf16(kf, qf[kk], sacc[ct], 0,0,0);
      }
    }
    __builtin_amdgcn_s_setprio(0);

    if (s == qb){
      const int qloc = w*32 + l31 - 4*hi;
      #pragma unroll
      for (int ct=0;ct<4;ct++)
        #pragma unroll
        for (int r=0;r<16;r++)
          if (ct*32 + (r&3) + 8*(r>>2) > qloc) sacc[ct][r] = -1e30f;
    }

    float pmax = sacc[0][0];
    #pragma unroll
    for (int ct=0;ct<4;ct++)
      #pragma unroll
      for (int r=0;r<16;r++) pmax = fmaxf(pmax, sacc[ct][r]);
    pmax = fmaxf(pmax, __shfl_xor(pmax, 32));

    if (!__all(pmax - mreg <= 8.0f)){       // T13 defer-rescale
      float mnew = fmaxf(mreg, pmax);
      float alpha = exp2_fast(mreg - mnew);
      mreg = mnew;
      lreg *= alpha;
      float aRow[16];
      #pragma unroll
      for (int r=0;r<16;r++) aRow[r] = __shfl(alpha, (r&3) + 8*(r>>2) + 4*hi);
      #pragma unroll
      for (int oc=0;oc<2;oc++)
        #pragma unroll
        for (int r=0;r<16;r++) o_acc[oc][r] *= aRow[r];
    }

    float sum = 0.f;
    #pragma unroll
    for (int ct=0;ct<4;ct++){
      float pv[16];
      #pragma unroll
      for (int r=0;r<16;r++){ pv[r] = exp2_fast(sacc[ct][r] - mreg); sum += pv[r]; }
      unsigned pk[8];
      #pragma unroll
      for (int t=0;t<8;t++)
        asm("v_cvt_pk_bf16_f32 %0, %1, %2" : "=v"(pk[t]) : "v"(pv[2*t]), "v"(pv[2*t+1]));
      #pragma unroll
      for (int kss=0;kss<2;kss++){
        const int W = 4*kss;
        unsigned x0 = pk[W],   x2 = pk[W+2];
        unsigned x1 = pk[W+1], x3 = pk[W+3];
        asm("v_permlane32_swap_b32 %0, %1" : "+v"(x0), "+v"(x2));
        asm("v_permlane32_swap_b32 %0, %1" : "+v"(x1), "+v"(x3));
        uint4 pau = {x0, x1, x2, x3};
        short8 pa = __builtin_bit_cast(short8, pau);
        __builtin_amdgcn_s_setprio(1);
        #pragma unroll
        for (int oc=0;oc<2;oc++){
          short8 vf = *(const short8*)(vl_ + vro[2*ct+kss] + oc*8192);
          o_acc[oc] = __builtin_amdgcn_mfma_f32_32x32x16_bf16(pa, vf, o_acc[oc], 0,0,0);
        }
        __builtin_amdgcn_s_setprio(0);
      }
    }
    sum += __shfl_xor(sum, 32);
    lreg += sum;

    __builtin_amdgcn_s_barrier();
  }

  const int bb = bh >> 4, hh = bh & 15;
  #pragma unroll
  for (int r=0;r<16;r++){
    float lf = __shfl(lreg, (r&3) + 8*(r>>2) + 4*hi);
    float inv = 1.0f / lf;
    int t = q0 + w*32 + (r&3) + 8*(r>>2) + 4*hi;
    size_t base = ((size_t)(bb*2048 + t))*1024 + (size_t)hh*64 + l31;
    ob[base]      = f2bf(o_acc[0][r] * inv);
    ob[base + 32] = f2bf(o_acc[1][r] * inv);
  }
}

extern "C" void kernel_launch(void* const* d_in, const int* in_sizes, int n_in,
                              void* d_out, int out_size, void* d_ws, size_t ws_size,
                              hipStream_t stream) {
  const float* x     = (const float*)d_in[0];   // [2,2048,1024]
  const float* w_qkv = (const float*)d_in[1];   // [1024,3072]
  const float* w_out = (const float*)d_in[2];   // [1024,1024]
  float* out = (float*)d_out;                   // [2,2048,1024] fp32

  char* ws = (char*)d_ws;
  short* xb    = (short*)(ws);                    // 8 MB  [4096][1024] bf16
  short* wqkvT = (short*)(ws + (8u  << 20));      // 6 MB  [3072][1024] bf16
  short* woutT = (short*)(ws + (14u << 20));      // 2 MB  [1024][1024] bf16
  short* qbuf  = (short*)(ws + (16u << 20));      // 8 MB  [32][2048][64] bf16 (prescaled)
  short* kbuf  = (short*)(ws + (24u << 20));      // 8 MB  [32][2048][64] bf16
  short* vbuf  = (short*)(ws + (32u << 20));      // 8 MB  [32][2048][64] bf16 (natural V)
  short* vtbuf = (short*)(ws + (40u << 20));      // 8 MB  [32][64][2048] bf16 (V^T)
  short* obuf  = vbuf;                            // alias: vbuf dead after transpose_v

  prep_kernel<<<4608, 256, 0, stream>>>(x, w_qkv, w_out, xb, wqkvT, woutT);
  gemm256_kernel<1><<<dim3(16,12), 512, 0, stream>>>(xb, wqkvT, nullptr,
                                                     qbuf, kbuf, vbuf, 4096, 3072, 1024);
  transpose_v_kernel<<<1024, 256, 0, stream>>>(vbuf, vtbuf);
  attn_kernel<<<dim3(512), 256, 0, stream>>>(qbuf, kbuf, vtbuf, obuf);
  gemm128_kernel<<<dim3(32,8), 256, 0, stream>>>(obuf, woutT, out, 4096, 1024, 1024);
}